// Round 12
// baseline (992.593 us; speedup 1.0000x reference)
//
#include <hip/hip_runtime.h>
#include <stdint.h>

// ============================================================================
// CPC forward on MI355X (gfx950).
// R2-R11 lesson: the register allocator ALWAYS evicts W_hh when its placement
// is discretionary (remat/spill, VGPR_Count pinned at the 4-wave 128 budget
// even with waves_per_eu(2,2)). R12: force placement via inline-asm MFMA with
// "a" (AGPR) operand constraints — W fragments and accumulators become
// AGPR-class live ranges (168+24 AGPR), arch working set ~55, total 247<=256
// at 2 waves/SIMD. kstep-7 (6 frags) streamed from a 48KB LDS slice via asm
// ds_read_b128 (+lgkmcnt(0)+sched_barrier, rule-18) so it can't be hoisted
// into registers. h row stride 264->288 f16 fixes the 8-way bank conflict.
// ============================================================================

typedef _Float16 f16;
typedef __attribute__((ext_vector_type(2))) _Float16 f16x2;
typedef __attribute__((ext_vector_type(8))) _Float16 f16x8;
typedef __attribute__((ext_vector_type(4))) float f32x4;

__device__ __forceinline__ f16x2 u2h(unsigned int x) { return __builtin_bit_cast(f16x2, x); }
__device__ __forceinline__ float sigm_(float x) { return __builtin_amdgcn_rcpf(1.f + __expf(-x)); }
__device__ __forceinline__ float tanh_(float x) { return 1.f - 2.f * __builtin_amdgcn_rcpf(__expf(2.f * x) + 1.f); }
__device__ __forceinline__ float gxe(const uint4& a, const uint4& b, const uint4& c, int s) {
  const uint4 v = (s < 8) ? a : (s < 16) ? b : c;
  const int r = s & 7;
  const unsigned d = (r < 2) ? v.x : (r < 4) ? v.y : (r < 6) ? v.z : v.w;
  return (float)u2h(d)[s & 1];
}

#define NTOT_LOSS 374784.0f  // 12 * 128 * 244

// MFMA with AGPR-pinned B (and AGPR accumulator): forces W residency.
#define MFMA_AA(ACC, AF, WF) \
  asm volatile("v_mfma_f32_16x16x32_f16 %0, %1, %2, %0" : "+a"(ACC) : "v"(AF), "a"(WF))
#define MFMA_AV(ACC, AF, WF) \
  asm volatile("v_mfma_f32_16x16x32_f16 %0, %1, %2, %0" : "+a"(ACC) : "v"(AF), "v"(WF))

// ---------------------------------------------------------------------------
// K0: weight conversion/swizzles + combined bias + accumulator zeroing.
// whhG3: [w 8][f 48][lane 64][e 8]; f=(g*2+nt)*8+ks; row=256g+32w+16nt+(lane&15);
//        k=32ks+8*(lane>>4)+e.  biasc[n]=b_ih[n]+(n<512?b_hh[n]:0).
// ---------------------------------------------------------------------------
__global__ void k_prep(const float* __restrict__ w1, const float* __restrict__ w2,
                       const float* __restrict__ wih, const float* __restrict__ whh,
                       const float* __restrict__ wkw, const float* __restrict__ bih,
                       const float* __restrict__ bhh,
                       f16* __restrict__ w1T, f16* __restrict__ w2T, f16* __restrict__ wihF,
                       f16* __restrict__ whhG3, f16* __restrict__ wkT,
                       float* __restrict__ biasc, float* __restrict__ accb) {
  const int stride = gridDim.x * blockDim.x;
  const int tid = blockIdx.x * blockDim.x + threadIdx.x;
  if (tid == 0) { accb[0] = 0.f; accb[1] = 0.f; }
  for (int i = tid; i < 768; i += stride) biasc[i] = bih[i] + (i < 512 ? bhh[i] : 0.f);
  for (int i = tid; i < 65536; i += stride) { int n = i >> 8, k = i & 255; w1T[i] = (f16)w1[k * 256 + n]; }
  for (int i = tid; i < 32768; i += stride) { int n = i >> 8, k = i & 255; w2T[i] = (f16)w2[k * 128 + n]; }
  for (int i = tid; i < 98304; i += stride) wihF[i] = (f16)wih[i];
  for (int i = tid; i < 196608; i += stride) {
    const int e = i & 7, lane = (i >> 3) & 63, rest = i >> 9;       // rest = w*48+f
    const int w = rest / 48, f = rest % 48;
    const int ks = f & 7, gnt = f >> 3, g = gnt >> 1, nt = gnt & 1;
    const int cl = lane & 15, hi = lane >> 4;
    const int row = g * 256 + w * 32 + nt * 16 + cl;
    const int k = ks * 32 + hi * 8 + e;
    whhG3[i] = (f16)whh[row * 256 + k];
  }
  for (int i = tid; i < 393216; i += stride) {
    int kk = i >> 15, rem = i & 32767, d = rem >> 8, c = rem & 255;
    wkT[i] = (f16)wkw[(kk << 15) + c * 128 + d];
  }
}

// ---------------------------------------------------------------------------
// Generic 64x64-tile f16 MFMA GEMM. GXS=true writes the k_gru gx swizzle.
// ---------------------------------------------------------------------------
template <int KTOT, bool AF32, bool RELU, bool GXS>
__global__ __launch_bounds__(256) void k_gemm64(const void* __restrict__ Aptr,
                                                const f16* __restrict__ BT,
                                                const float* __restrict__ bias,
                                                f16* __restrict__ out, const int NT) {
  __shared__ __align__(16) f16 Al[64][40];
  __shared__ __align__(16) f16 Bl[64][40];
  const int m0 = blockIdx.x * 64;
  const int n0 = blockIdx.y * 64;
  const int t = threadIdx.x;
  const int w = t >> 6, l = t & 63, lr = l & 15, lg = l >> 4;
  const int arow = t >> 2, akq = (t & 3) * 8;
  f32x4 acc[4] = {};
  for (int ks = 0; ks < KTOT / 32; ++ks) {
    const int kc = ks * 32;
    __syncthreads();
    if constexpr (AF32) {
      const float* src = (const float*)Aptr + (size_t)(m0 + arow) * KTOT + kc + akq;
      float4 v0 = *(const float4*)src;
      float4 v1 = *(const float4*)(src + 4);
      f16x8 hv = {(f16)v0.x, (f16)v0.y, (f16)v0.z, (f16)v0.w,
                  (f16)v1.x, (f16)v1.y, (f16)v1.z, (f16)v1.w};
      *(f16x8*)&Al[arow][akq] = hv;
    } else {
      const f16* src = (const f16*)Aptr + (size_t)(m0 + arow) * KTOT + kc + akq;
      *(f16x8*)&Al[arow][akq] = *(const f16x8*)src;
    }
    *(f16x8*)&Bl[arow][akq] = *(const f16x8*)(BT + (size_t)(n0 + arow) * KTOT + kc + akq);
    __syncthreads();
    f16x8 af = *(const f16x8*)&Al[16 * w + lr][lg * 8];
#pragma unroll
    for (int nt = 0; nt < 4; ++nt) {
      f16x8 bf = *(const f16x8*)&Bl[nt * 16 + lr][lg * 8];
      acc[nt] = __builtin_amdgcn_mfma_f32_16x16x32_f16(af, bf, acc[nt], 0, 0, 0);
    }
  }
#pragma unroll
  for (int nt = 0; nt < 4; ++nt) {
    const int n = n0 + nt * 16 + lr;
    const float bb = bias[n];
#pragma unroll
    for (int r = 0; r < 4; ++r) {
      const int m = m0 + 16 * w + lg * 4 + r;
      float v = acc[nt][r] + bb;
      if (RELU) v = fmaxf(v, 0.f);
      if constexpr (GXS) {
        const int b = m >> 8, tt2 = m & 255;
        const int bc = b >> 4, ml = b & 15, hi2 = ml >> 2, i2 = ml & 3;
        const int g = n >> 8, col = n & 255;
        const int w2 = col >> 5, nt2 = (col >> 4) & 1, cl2 = col & 15;
        const int lane2 = hi2 * 16 + cl2;
        const int slot = (g * 2 + nt2) * 4 + i2;
        out[((((size_t)bc * 256 + tt2) * 8 + w2) * 64 + lane2) * 24 + slot] = (f16)v;
      } else {
        out[(size_t)m * NT + n] = (f16)v;
      }
    }
  }
}

// ---------------------------------------------------------------------------
// K2: z = l2norm(h1 @ w2T + b2). Writes z f32 (output) + z f16 (workspace).
// ---------------------------------------------------------------------------
__global__ __launch_bounds__(256) void k_enc2(const f16* __restrict__ A, const f16* __restrict__ BT,
                                              const float* __restrict__ bias,
                                              float* __restrict__ zf32, f16* __restrict__ zf16) {
  __shared__ __align__(16) f16 Al[64][40];
  __shared__ __align__(16) f16 Bl[128][40];
  const int m0 = blockIdx.x * 64;
  const int t = threadIdx.x;
  const int w = t >> 6, l = t & 63, lr = l & 15, lg = l >> 4;
  const int arow = t >> 2, akq = (t & 3) * 8;
  f32x4 acc[8] = {};
  for (int ks = 0; ks < 8; ++ks) {
    const int kc = ks * 32;
    __syncthreads();
    *(f16x8*)&Al[arow][akq] = *(const f16x8*)(A + (size_t)(m0 + arow) * 256 + kc + akq);
#pragma unroll
    for (int hh = 0; hh < 2; ++hh) {
      const int brow = arow + 64 * hh;
      *(f16x8*)&Bl[brow][akq] = *(const f16x8*)(BT + (size_t)brow * 256 + kc + akq);
    }
    __syncthreads();
    f16x8 af = *(const f16x8*)&Al[16 * w + lr][lg * 8];
#pragma unroll
    for (int nt = 0; nt < 8; ++nt) {
      f16x8 bf = *(const f16x8*)&Bl[nt * 16 + lr][lg * 8];
      acc[nt] = __builtin_amdgcn_mfma_f32_16x16x32_f16(af, bf, acc[nt], 0, 0, 0);
    }
  }
  float v[8][4];
#pragma unroll
  for (int nt = 0; nt < 8; ++nt) {
    const float bb = bias[nt * 16 + lr];
#pragma unroll
    for (int r = 0; r < 4; ++r) v[nt][r] = acc[nt][r] + bb;
  }
#pragma unroll
  for (int r = 0; r < 4; ++r) {
    float ss = 0.f;
#pragma unroll
    for (int nt = 0; nt < 8; ++nt) ss += v[nt][r] * v[nt][r];
    ss += __shfl_xor(ss, 1); ss += __shfl_xor(ss, 2); ss += __shfl_xor(ss, 4); ss += __shfl_xor(ss, 8);
    const float scl = 1.f / fmaxf(sqrtf(ss), 1e-12f);
    const int m = m0 + 16 * w + lg * 4 + r;
#pragma unroll
    for (int nt = 0; nt < 8; ++nt) {
      const int n = nt * 16 + lr;
      const float z = v[nt][r] * scl;
      zf32[(size_t)m * 128 + n] = z;
      zf16[(size_t)m * 128 + n] = (f16)z;
    }
  }
}

// ---------------------------------------------------------------------------
// K4: MFMA GRU scan, AGPR-pinned W. 8 blocks x 512 threads (2 waves/SIMD).
// Wave w owns h-cols [32w,32w+32) x 3 gates = 6 (g,nt) x 8 ksteps fragments.
// ksteps 0..6 resident in AGPR (42 frags = 168 AGPR) via "a" asm constraint;
// kstep 7 (6 frags) streamed from a 48KB LDS slice via asm ds_read_b128.
// acc in AGPR ("+a", 24). Arch working set ~55 -> total ~247 <= 256.
// h tile [16][288] f16 (stride 144 dw = 16 mod 32 -> conflict-free b128).
// ---------------------------------------------------------------------------
__global__ __attribute__((amdgpu_flat_work_group_size(512, 512), amdgpu_waves_per_eu(2, 2)))
void k_gru(const f16* __restrict__ gxS, const f16* __restrict__ whhG3,
           const float* __restrict__ bhh, f16* __restrict__ cf16) {
  __shared__ __align__(16) f16 h_lds[2][16][288];   // 18KB
  __shared__ __align__(16) f16 w7_lds[8][6][64][8]; // 48KB (kstep-7 slice)
  const int bc = blockIdx.x;
  const int t = threadIdx.x;
  const int w = t >> 6, lane = t & 63;
  const int hi = lane >> 4, cl = lane & 15;
  // ---- preload 42 resident W frags + stage kstep-7 slice to LDS ----
  f16x8 Wf[42];
  {
    const f16* wbase = whhG3 + (size_t)w * 24576 + (size_t)lane * 8;
#pragma unroll
    for (int gn = 0; gn < 6; ++gn) {
#pragma unroll
      for (int ks = 0; ks < 7; ++ks)
        Wf[gn * 7 + ks] = *(const f16x8*)(wbase + (size_t)(gn * 8 + ks) * 512);
      *(f16x8*)&w7_lds[w][gn][lane][0] = *(const f16x8*)(wbase + (size_t)(gn * 8 + 7) * 512);
    }
  }
  const float bhn0 = bhh[512 + w * 32 + cl];
  const float bhn1 = bhh[512 + w * 32 + 16 + cl];
  // zero h buffer 0 (2*16*288 f16 = 4608 u32; just zero both buffers: 4608)
  for (int idx = t; idx < 4608, idx < 2 * 16 * 288 / 2; idx += 512) ((uint32_t*)h_lds)[idx] = 0u;
  float ho[2][4] = {};
  const f16* gxp = gxS + (((size_t)bc * 256 * 8 + w) * 64 + lane) * 24;
  f16* cfb = cf16 + ((size_t)(16 * bc + 4 * hi)) * 256 + w * 32 + cl;
  __syncthreads();
#pragma unroll 1
  for (int tt = 0; tt < 256; ++tt) {
    const int cur = tt & 1;
    // gx loads issued first (consumed after MFMA, latency hidden)
    const f16* gxt = gxp + (size_t)tt * 12288;
    const uint4 gA = *(const uint4*)(gxt);
    const uint4 gB = *(const uint4*)(gxt + 8);
    const uint4 gC = *(const uint4*)(gxt + 16);
    // issue kstep-7 W reads early (asm ds_read: cannot be hoisted to regs)
    f16x8 w7[6];
#pragma unroll
    for (int gn = 0; gn < 6; ++gn) {
      const f16* a7 = &w7_lds[w][gn][lane][0];
      asm volatile("ds_read_b128 %0, %1" : "=v"(w7[gn]) : "v"((uint32_t)(size_t)a7));
    }
    // ---- MFMA ksteps 0..6 from AGPR-resident W ----
    f32x4 acc[6] = {};
#pragma unroll
    for (int ks = 0; ks < 7; ++ks) {
      const f16x8 af = *(const f16x8*)&h_lds[cur][cl][ks * 32 + hi * 8];
      MFMA_AA(acc[0], af, Wf[0 * 7 + ks]);
      MFMA_AA(acc[1], af, Wf[1 * 7 + ks]);
      MFMA_AA(acc[2], af, Wf[2 * 7 + ks]);
      MFMA_AA(acc[3], af, Wf[3 * 7 + ks]);
      MFMA_AA(acc[4], af, Wf[4 * 7 + ks]);
      MFMA_AA(acc[5], af, Wf[5 * 7 + ks]);
    }
    // ---- kstep 7 from LDS-streamed W (rule-18 fence before use) ----
    {
      const f16x8 af7 = *(const f16x8*)&h_lds[cur][cl][7 * 32 + hi * 8];
      asm volatile("s_waitcnt lgkmcnt(0)");
      __builtin_amdgcn_sched_barrier(0);
      MFMA_AV(acc[0], af7, w7[0]);
      MFMA_AV(acc[1], af7, w7[1]);
      MFMA_AV(acc[2], af7, w7[2]);
      MFMA_AV(acc[3], af7, w7[3]);
      MFMA_AV(acc[4], af7, w7[4]);
      MFMA_AV(acc[5], af7, w7[5]);
    }
    // ---- lane-local gates: 8 outputs = 2 nt x 4 batches ----
    f16* hb = &h_lds[cur ^ 1][0][0];
    f16* cfo = cfb + (size_t)tt * 32768;
#pragma unroll
    for (int nt = 0; nt < 2; ++nt) {
      const float bhn = nt ? bhn1 : bhn0;
#pragma unroll
      for (int i = 0; i < 4; ++i) {
        const float xr = gxe(gA, gB, gC, (0 + nt) * 4 + i);
        const float xz = gxe(gA, gB, gC, (2 + nt) * 4 + i);
        const float xn = gxe(gA, gB, gC, (4 + nt) * 4 + i);
        const float r = sigm_(xr + acc[nt][i]);          // b_ih+b_hh folded in gx
        const float z = sigm_(xz + acc[2 + nt][i]);
        const float n = tanh_(xn + r * (acc[4 + nt][i] + bhn));
        const float h = (1.f - z) * n + z * ho[nt][i];
        ho[nt][i] = h;
        const f16 hh = (f16)h;
        hb[(4 * hi + i) * 288 + w * 32 + nt * 16 + cl] = hh;
        cfo[i * 256 + nt * 16] = hh;
      }
    }
    __syncthreads();
  }
}

// ---------------------------------------------------------------------------
// K4b: c_seq f32 output = widen + transpose cf16[t][b][c] -> cf32[b][t][c].
// ---------------------------------------------------------------------------
__global__ void k_c32(const f16* __restrict__ cf, float* __restrict__ o) {
  const size_t idx = (size_t)(blockIdx.x * blockDim.x + threadIdx.x) * 8;
  const int c = idx & 255;
  const int b = (idx >> 8) & 127;
  const int t2 = idx >> 15;
  const f16x8 v = *(const f16x8*)(cf + ((size_t)t2 * 128 + b) * 256 + c);
  float* op = o + ((size_t)b * 256 + t2) * 256 + c;
  float4 a = {(float)v[0], (float)v[1], (float)v[2], (float)v[3]};
  float4 bb = {(float)v[4], (float)v[5], (float)v[6], (float)v[7]};
  *(float4*)op = a;
  *(float4*)(op + 4) = bb;
}

// ---------------------------------------------------------------------------
// K5: fused preds -> l2norm -> logits -> online LSE / pos / neg-max -> loss&acc.
// ---------------------------------------------------------------------------
__global__ __launch_bounds__(256) void k_cpc(const f16* __restrict__ cf16, const f16* __restrict__ zf16,
                                             const f16* __restrict__ wkT, const float* __restrict__ wkb,
                                             float* __restrict__ accb) {
  __shared__ __align__(16) f16 SMc[64 * 264];
  __shared__ __align__(16) f16 Bl[128][40];
  __shared__ __align__(16) f16 P[64][136];
  __shared__ float red[2];
  const int tc = blockIdx.x, b = blockIdx.y, kk = blockIdx.z;
  const int t0 = tc * 64;
  const int t = threadIdx.x;
  const int w = t >> 6, l = t & 63, lr = l & 15, lg = l >> 4;
  {
    const uint32_t* srcu = (const uint32_t*)cf16 + (size_t)t0 * 16384 + (size_t)b * 128;
    uint32_t* dst = (uint32_t*)SMc;
#pragma unroll
    for (int it = 0; it < 32; ++it) {
      const int idx = it * 256 + t, row = idx >> 7, cw = idx & 127;
      dst[row * 132 + cw] = srcu[(size_t)row * 16384 + cw];
    }
  }
  f32x4 acc[8] = {};
  for (int ks = 0; ks < 8; ++ks) {
    __syncthreads();
    {
      const uint32_t* bsrc = (const uint32_t*)(wkT + ((size_t)kk << 15));
      uint32_t* bd = (uint32_t*)Bl;
#pragma unroll
      for (int it = 0; it < 8; ++it) {
        const int idx = it * 256 + t, row = idx >> 4, kw = idx & 15;
        bd[row * 20 + kw] = bsrc[row * 128 + ks * 16 + kw];
      }
    }
    __syncthreads();
    f16x8 af = *(const f16x8*)&SMc[(16 * w + lr) * 264 + ks * 32 + lg * 8];
#pragma unroll
    for (int nt = 0; nt < 8; ++nt) {
      f16x8 bf = *(const f16x8*)&Bl[nt * 16 + lr][lg * 8];
      acc[nt] = __builtin_amdgcn_mfma_f32_16x16x32_f16(af, bf, acc[nt], 0, 0, 0);
    }
  }
  {
    float v[8][4];
#pragma unroll
    for (int nt = 0; nt < 8; ++nt) {
      const float bb = wkb[kk * 128 + nt * 16 + lr];
#pragma unroll
      for (int r = 0; r < 4; ++r) v[nt][r] = acc[nt][r] + bb;
    }
#pragma unroll
    for (int r = 0; r < 4; ++r) {
      float ss = 0.f;
#pragma unroll
      for (int nt = 0; nt < 8; ++nt) ss += v[nt][r] * v[nt][r];
      ss += __shfl_xor(ss, 1); ss += __shfl_xor(ss, 2); ss += __shfl_xor(ss, 4); ss += __shfl_xor(ss, 8);
      const float scl = 1.f / fmaxf(sqrtf(ss), 1e-12f);
#pragma unroll
      for (int nt = 0; nt < 8; ++nt)
        P[16 * w + lg * 4 + r][nt * 16 + lr] = (f16)(v[nt][r] * scl);
    }
  }
  __syncthreads();
  float m_run[4], s_run[4], pos_v[4], neg_m[4];
#pragma unroll
  for (int r = 0; r < 4; ++r) { m_run[r] = -1e30f; s_run[r] = 0.f; pos_v[r] = -1e30f; neg_m[r] = -1e30f; }
  for (int sc = 0; sc < 4; ++sc) {
    __syncthreads();
    {
      const uint32_t* zsrc = (const uint32_t*)(zf16 + ((size_t)b * 256 + sc * 64) * 128);
      uint32_t* zd = (uint32_t*)SMc;
#pragma unroll
      for (int it = 0; it < 16; ++it) {
        const int idx = it * 256 + t, row = idx >> 6, cw = idx & 63;
        zd[row * 68 + cw] = zsrc[row * 64 + cw];
      }
    }
    __syncthreads();
    f32x4 sa[4] = {};
#pragma unroll
    for (int ks = 0; ks < 4; ++ks) {
      f16x8 af = *(const f16x8*)&P[16 * w + lr][ks * 32 + lg * 8];
#pragma unroll
      for (int nt = 0; nt < 4; ++nt) {
        f16x8 bf = *(const f16x8*)&SMc[(nt * 16 + lr) * 136 + ks * 32 + lg * 8];
        sa[nt] = __builtin_amdgcn_mfma_f32_16x16x32_f16(af, bf, sa[nt], 0, 0, 0);
      }
    }
#pragma unroll
    for (int r = 0; r < 4; ++r) {
      const int trow = t0 + 16 * w + lg * 4 + r;
      const int pos_s = trow + kk + 1;
      float vv[4];
#pragma unroll
      for (int nt = 0; nt < 4; ++nt) vv[nt] = sa[nt][r] * 10.f;
      float cm = fmaxf(fmaxf(vv[0], vv[1]), fmaxf(vv[2], vv[3]));
      cm = fmaxf(cm, __shfl_xor(cm, 1)); cm = fmaxf(cm, __shfl_xor(cm, 2));
      cm = fmaxf(cm, __shfl_xor(cm, 4)); cm = fmaxf(cm, __shfl_xor(cm, 8));
      const float nm = fmaxf(m_run[r], cm);
      float ps = __expf(vv[0] - nm) + __expf(vv[1] - nm) + __expf(vv[2] - nm) + __expf(vv[3] - nm);
      ps += __shfl_xor(ps, 1); ps += __shfl_xor(ps, 2); ps += __shfl_xor(ps, 4); ps += __shfl_xor(ps, 8);
      s_run[r] = s_run[r] * __expf(m_run[r] - nm) + ps;
      m_run[r] = nm;
      const int sbase = sc * 64 + lr;
#pragma unroll
      for (int nt = 0; nt < 4; ++nt) {
        const int s = sbase + nt * 16;
        if (s == pos_s) pos_v[r] = vv[nt];
        else neg_m[r] = fmaxf(neg_m[r], vv[nt]);
      }
    }
  }
  __syncthreads();
  if (t == 0) { red[0] = 0.f; red[1] = 0.f; }
  __syncthreads();
  float lsum = 0.f, csum = 0.f;
#pragma unroll
  for (int r = 0; r < 4; ++r) {
    float pv = pos_v[r], ng = neg_m[r];
    pv = fmaxf(pv, __shfl_xor(pv, 1)); pv = fmaxf(pv, __shfl_xor(pv, 2));
    pv = fmaxf(pv, __shfl_xor(pv, 4)); pv = fmaxf(pv, __shfl_xor(pv, 8));
    ng = fmaxf(ng, __shfl_xor(ng, 1)); ng = fmaxf(ng, __shfl_xor(ng, 2));
    ng = fmaxf(ng, __shfl_xor(ng, 4)); ng = fmaxf(ng, __shfl_xor(ng, 8));
    const int trow = t0 + 16 * w + lg * 4 + r;
    if (lr == 0 && trow < 244) {
      const float lse = m_run[r] + __logf(s_run[r]);
      lsum += lse - pv;
      csum += (pv >= ng) ? 1.f : 0.f;
    }
  }
  if (lr == 0) { atomicAdd(&red[0], lsum); atomicAdd(&red[1], csum); }
  __syncthreads();
  if (t == 0) { atomicAdd(&accb[0], red[0]); atomicAdd(&accb[1], red[1]); }
}

__global__ void k_fin(const float* __restrict__ accb, float* __restrict__ out) {
  out[0] = accb[0] * (1.0f / NTOT_LOSS);
  out[1] = accb[1] * (100.0f / NTOT_LOSS);
}

// ---------------------------------------------------------------------------
extern "C" void kernel_launch(void* const* d_in, const int* in_sizes, int n_in,
                              void* d_out, int out_size, void* d_ws, size_t ws_size,
                              hipStream_t stream) {
  (void)in_sizes; (void)n_in; (void)out_size; (void)ws_size;
  const float* rr  = (const float*)d_in[0];
  const float* w1  = (const float*)d_in[1];
  const float* b1  = (const float*)d_in[2];
  const float* w2  = (const float*)d_in[3];
  const float* b2  = (const float*)d_in[4];
  const float* wih = (const float*)d_in[5];
  const float* whh = (const float*)d_in[6];
  const float* bih = (const float*)d_in[7];
  const float* bhh = (const float*)d_in[8];
  const float* wkw = (const float*)d_in[9];
  const float* wkb = (const float*)d_in[10];
  float* out = (float*)d_out;
  char* ws = (char*)d_ws;

  const size_t GX_B = (size_t)32768 * 768 * 2;
  f16* gxS  = (f16*)ws;
  f16* h1   = (f16*)ws;  // alias: h1 dead before gxS written
  f16* zf16 = (f16*)(ws + GX_B);
  f16* cf16 = (f16*)(ws + GX_B + 8388608);
  f16* w1T  = (f16*)(ws + GX_B + 8388608 + 16777216);
  f16* w2T  = w1T + 65536;
  f16* wihF = w2T + 32768;
  f16* whhG3 = wihF + 98304;
  f16* wkT  = whhG3 + 196608;
  float* biasc = (float*)(wkT + 393216);
  float* accb  = biasc + 768;

  float* zf32 = out + 2;
  float* cf32 = out + 2 + 4194304;

  k_prep<<<256, 256, 0, stream>>>(w1, w2, wih, whh, wkw, bih, bhh,
                                  w1T, w2T, wihF, whhG3, wkT, biasc, accb);
  k_gemm64<256, true, true, false><<<dim3(512, 4), 256, 0, stream>>>(rr, w1T, b1, h1, 256);
  k_enc2<<<dim3(512), 256, 0, stream>>>(h1, w2T, b2, zf32, zf16);
  k_gemm64<128, false, false, true><<<dim3(512, 12), 256, 0, stream>>>(zf16, wihF, biasc, gxS, 768);
  k_gru<<<8, 512, 0, stream>>>(gxS, whhG3, bhh, cf16);
  k_c32<<<4096, 256, 0, stream>>>(cf16, cf32);
  k_cpc<<<dim3(4, 128, 12), 256, 0, stream>>>(cf16, zf16, wkT, wkb, accb);
  k_fin<<<1, 1, 0, stream>>>(accb, out);
}

// Round 13
// 624.667 us; speedup vs baseline: 1.5890x; 1.5890x over previous
//
#include <hip/hip_runtime.h>
#include <stdint.h>

// ============================================================================
// CPC forward on MI355X (gfx950).
// R2-R12 conclusion: W_hh register residency is unachievable (unified file
// 512 regs/SIMD total; every allocator-level and asm-level forcing attempt
// failed or serialized). f16-streaming floor = 384KB/CU/step / 128B/cyc =
// 3072 cyc/step = 328us (R2). k_gru reverted to R2's fdot2 version.
// R13 experiment: k_cpc kk-merge — grid (4,128,12)->(4,128), c-tile staged
// ONCE per (tc,b) (was 12x), kk loop inside with dedicated LDS buffers
// (SMc 33K + Bl 10K + P 17K + Zl 17K = 79KB, 2 blocks/CU).
// ============================================================================

typedef _Float16 f16;
typedef __attribute__((ext_vector_type(2))) _Float16 f16x2;
typedef __attribute__((ext_vector_type(8))) _Float16 f16x8;
typedef __attribute__((ext_vector_type(4))) float f32x4;

__device__ __forceinline__ f16x2 u2h(unsigned int x) { return __builtin_bit_cast(f16x2, x); }
__device__ __forceinline__ float sigm_(float x) { return __builtin_amdgcn_rcpf(1.f + __expf(-x)); }
__device__ __forceinline__ float tanh_(float x) { return 1.f - 2.f * __builtin_amdgcn_rcpf(__expf(2.f * x) + 1.f); }

#define NTOT_LOSS 374784.0f  // 12 * 128 * 244

// ---------------------------------------------------------------------------
// K0: convert weights to f16 (transposing where the GEMMs want [N][K]),
//     zero the loss/accuracy accumulators.   (R2 version)
// ---------------------------------------------------------------------------
__global__ void k_prep(const float* __restrict__ w1, const float* __restrict__ w2,
                       const float* __restrict__ wih, const float* __restrict__ whh,
                       const float* __restrict__ wkw,
                       f16* __restrict__ w1T, f16* __restrict__ w2T, f16* __restrict__ wihF,
                       f16* __restrict__ whhF, f16* __restrict__ wkT, float* __restrict__ accb) {
  const int stride = gridDim.x * blockDim.x;
  const int tid = blockIdx.x * blockDim.x + threadIdx.x;
  if (tid == 0) { accb[0] = 0.f; accb[1] = 0.f; }
  // w1 (256k x 256n) -> w1T[n][k]
  for (int i = tid; i < 65536; i += stride) { int n = i >> 8, k = i & 255; w1T[i] = (f16)w1[k * 256 + n]; }
  // w2 (256k x 128n) -> w2T[n][k]
  for (int i = tid; i < 32768; i += stride) { int n = i >> 8, k = i & 255; w2T[i] = (f16)w2[k * 128 + n]; }
  // W_ih (768 x 128) already [N][K]
  for (int i = tid; i < 98304; i += stride) wihF[i] = (f16)wih[i];
  // W_hh (768 x 256) row-major, consumed row-per-thread in k_gru
  for (int i = tid; i < 196608; i += stride) whhF[i] = (f16)whh[i];
  // Wk_w (12,256c,128d) -> wkT[kk][d][c]
  for (int i = tid; i < 393216; i += stride) {
    int kk = i >> 15, rem = i & 32767, d = rem >> 8, c = rem & 255;
    wkT[i] = (f16)wkw[(kk << 15) + c * 128 + d];
  }
}

// ---------------------------------------------------------------------------
// Generic 64x64-tile f16 MFMA GEMM (R2 version).
// ---------------------------------------------------------------------------
template <int KTOT, bool AF32, bool RELU>
__global__ __launch_bounds__(256) void k_gemm64(const void* __restrict__ Aptr,
                                                const f16* __restrict__ BT,
                                                const float* __restrict__ bias,
                                                f16* __restrict__ out, const int NT) {
  __shared__ __align__(16) f16 Al[64][40];
  __shared__ __align__(16) f16 Bl[64][40];
  const int m0 = blockIdx.x * 64;
  const int n0 = blockIdx.y * 64;
  const int t = threadIdx.x;
  const int w = t >> 6, l = t & 63, lr = l & 15, lg = l >> 4;
  const int arow = t >> 2, akq = (t & 3) * 8;
  f32x4 acc[4] = {};
  for (int ks = 0; ks < KTOT / 32; ++ks) {
    const int kc = ks * 32;
    __syncthreads();
    if constexpr (AF32) {
      const float* src = (const float*)Aptr + (size_t)(m0 + arow) * KTOT + kc + akq;
      float4 v0 = *(const float4*)src;
      float4 v1 = *(const float4*)(src + 4);
      f16x8 hv = {(f16)v0.x, (f16)v0.y, (f16)v0.z, (f16)v0.w,
                  (f16)v1.x, (f16)v1.y, (f16)v1.z, (f16)v1.w};
      *(f16x8*)&Al[arow][akq] = hv;
    } else {
      const f16* src = (const f16*)Aptr + (size_t)(m0 + arow) * KTOT + kc + akq;
      *(f16x8*)&Al[arow][akq] = *(const f16x8*)src;
    }
    *(f16x8*)&Bl[arow][akq] = *(const f16x8*)(BT + (size_t)(n0 + arow) * KTOT + kc + akq);
    __syncthreads();
    f16x8 af = *(const f16x8*)&Al[16 * w + lr][lg * 8];
#pragma unroll
    for (int nt = 0; nt < 4; ++nt) {
      f16x8 bf = *(const f16x8*)&Bl[nt * 16 + lr][lg * 8];
      acc[nt] = __builtin_amdgcn_mfma_f32_16x16x32_f16(af, bf, acc[nt], 0, 0, 0);
    }
  }
#pragma unroll
  for (int nt = 0; nt < 4; ++nt) {
    const int n = n0 + nt * 16 + lr;
    const float bb = bias[n];
#pragma unroll
    for (int r = 0; r < 4; ++r) {
      const int m = m0 + 16 * w + lg * 4 + r;
      float v = acc[nt][r] + bb;
      if (RELU) v = fmaxf(v, 0.f);
      out[(size_t)m * NT + n] = (f16)v;
    }
  }
}

// ---------------------------------------------------------------------------
// K2: z = l2norm(h1 @ w2T + b2). (R2 version)
// ---------------------------------------------------------------------------
__global__ __launch_bounds__(256) void k_enc2(const f16* __restrict__ A, const f16* __restrict__ BT,
                                              const float* __restrict__ bias,
                                              float* __restrict__ zf32, f16* __restrict__ zf16) {
  __shared__ __align__(16) f16 Al[64][40];
  __shared__ __align__(16) f16 Bl[128][40];
  const int m0 = blockIdx.x * 64;
  const int t = threadIdx.x;
  const int w = t >> 6, l = t & 63, lr = l & 15, lg = l >> 4;
  const int arow = t >> 2, akq = (t & 3) * 8;
  f32x4 acc[8] = {};
  for (int ks = 0; ks < 8; ++ks) {
    const int kc = ks * 32;
    __syncthreads();
    *(f16x8*)&Al[arow][akq] = *(const f16x8*)(A + (size_t)(m0 + arow) * 256 + kc + akq);
#pragma unroll
    for (int hh = 0; hh < 2; ++hh) {
      const int brow = arow + 64 * hh;
      *(f16x8*)&Bl[brow][akq] = *(const f16x8*)(BT + (size_t)brow * 256 + kc + akq);
    }
    __syncthreads();
    f16x8 af = *(const f16x8*)&Al[16 * w + lr][lg * 8];
#pragma unroll
    for (int nt = 0; nt < 8; ++nt) {
      f16x8 bf = *(const f16x8*)&Bl[nt * 16 + lr][lg * 8];
      acc[nt] = __builtin_amdgcn_mfma_f32_16x16x32_f16(af, bf, acc[nt], 0, 0, 0);
    }
  }
  float v[8][4];
#pragma unroll
  for (int nt = 0; nt < 8; ++nt) {
    const float bb = bias[nt * 16 + lr];
#pragma unroll
    for (int r = 0; r < 4; ++r) v[nt][r] = acc[nt][r] + bb;
  }
#pragma unroll
  for (int r = 0; r < 4; ++r) {
    float ss = 0.f;
#pragma unroll
    for (int nt = 0; nt < 8; ++nt) ss += v[nt][r] * v[nt][r];
    ss += __shfl_xor(ss, 1); ss += __shfl_xor(ss, 2); ss += __shfl_xor(ss, 4); ss += __shfl_xor(ss, 8);
    const float scl = 1.f / fmaxf(sqrtf(ss), 1e-12f);
    const int m = m0 + 16 * w + lg * 4 + r;
#pragma unroll
    for (int nt = 0; nt < 8; ++nt) {
      const int n = nt * 16 + lr;
      const float z = v[nt][r] * scl;
      zf32[(size_t)m * 128 + n] = z;
      zf16[(size_t)m * 128 + n] = (f16)z;
    }
  }
}

// ---------------------------------------------------------------------------
// K4: GRU scan (R2 version — the 328us f16-streaming floor). 128 blocks x
// 768 threads; thread o: gate g=o>>8, col c=o&255; W row streamed from L2
// (compiler remat), h broadcast via wave-uniform ds_read_b128.
// ---------------------------------------------------------------------------
__global__ __launch_bounds__(768, 3) void k_gru(const f16* __restrict__ gx, const f16* __restrict__ whh,
                                                const float* __restrict__ bhh,
                                                float* __restrict__ cout, f16* __restrict__ cf16) {
  __shared__ __align__(16) f16 h_lds[2][256];
  __shared__ float rz[2][256];
  const int b = blockIdx.x;
  const int o = threadIdx.x;
  const int g = o >> 8;
  const int c = o & 255;
  uint4 wv[32];
  {
    const uint4* wp = (const uint4*)(whh + (size_t)o * 256);
#pragma unroll
    for (int i = 0; i < 32; ++i) wv[i] = wp[i];
  }
  const float bh = bhh[o];
  if (o < 256) h_lds[0][o] = (f16)0.f;
  float h_own = 0.f;
  const f16* gxp = gx + (size_t)b * 256 * 768 + o;
  float* coutp = cout + (size_t)b * 256 * 256 + c;
  f16* cfp = cf16 + (size_t)b * 256 * 256 + c;
  __syncthreads();
#pragma unroll 1
  for (int tt = 0; tt < 256; ++tt) {
    const int cur = tt & 1;
    const float gxv = (float)gxp[tt * 768];
    float a0 = 0.f, a1 = 0.f, a2 = 0.f, a3 = 0.f;
    const uint4* hp = (const uint4*)(&h_lds[cur][0]);
#pragma unroll
    for (int i = 0; i < 32; ++i) {
      const uint4 hv = hp[i];  // wave-uniform address -> LDS broadcast
      a0 = __builtin_amdgcn_fdot2(u2h(wv[i].x), u2h(hv.x), a0, false);
      a1 = __builtin_amdgcn_fdot2(u2h(wv[i].y), u2h(hv.y), a1, false);
      a2 = __builtin_amdgcn_fdot2(u2h(wv[i].z), u2h(hv.z), a2, false);
      a3 = __builtin_amdgcn_fdot2(u2h(wv[i].w), u2h(hv.w), a3, false);
    }
    const float dot = (a0 + a1) + (a2 + a3) + bh;
    if (g < 2) rz[g][c] = sigm_(gxv + dot);
    __syncthreads();
    if (g == 2) {
      const float r = rz[0][c], zz = rz[1][c];
      const float n = tanh_(gxv + r * dot);
      const float hn = (1.f - zz) * n + zz * h_own;
      h_own = hn;
      h_lds[cur ^ 1][c] = (f16)hn;
      coutp[tt * 256] = hn;
      cfp[tt * 256] = (f16)hn;
    }
    __syncthreads();
  }
}

// ---------------------------------------------------------------------------
// K5: fused preds -> l2norm -> logits -> online LSE/pos/negmax -> loss&acc.
// R13: kk-merged. grid (tc=4, b=128), 256 threads. c-tile staged ONCE,
// kk loop inside; dedicated LDS buffers (79KB total, 2 blocks/CU).
// Barrier safety: preds ks-loop barriers separate previous kk's logits
// (reads P, Zl) from this kk's P/Zl rewrites.
// ---------------------------------------------------------------------------
__global__ __launch_bounds__(256) void k_cpc(const f16* __restrict__ cf16, const f16* __restrict__ zf16,
                                             const f16* __restrict__ wkT, const float* __restrict__ wkb,
                                             float* __restrict__ accb) {
  __shared__ __align__(16) f16 SMc[64 * 264];   // c-tile [64][264]
  __shared__ __align__(16) f16 Bl[128][40];
  __shared__ __align__(16) f16 P[64][136];
  __shared__ __align__(16) f16 Zl[64 * 136];    // z chunk [64][136]
  __shared__ float red[2];
  const int tc = blockIdx.x, b = blockIdx.y;
  const int t0 = tc * 64;
  const int t = threadIdx.x;
  const int w = t >> 6, l = t & 63, lr = l & 15, lg = l >> 4;
  // ---- stage c tile ONCE (64 x 256 = 8192 u32) ----
  {
    const uint32_t* src = (const uint32_t*)(cf16 + ((size_t)b * 256 + t0) * 256);
    uint32_t* dst = (uint32_t*)SMc;
#pragma unroll
    for (int it = 0; it < 32; ++it) {
      const int idx = it * 256 + t, row = idx >> 7, cw = idx & 127;
      dst[row * 132 + cw] = src[row * 128 + cw];
    }
  }
  float lsum = 0.f, csum = 0.f;
#pragma unroll 1
  for (int kk = 0; kk < 12; ++kk) {
    // ---- preds GEMM: (64 x 128) = c(64x256) @ Wk^T ----
    f32x4 acc[8] = {};
    for (int ks = 0; ks < 8; ++ks) {
      __syncthreads();
      {
        const uint32_t* bsrc = (const uint32_t*)(wkT + ((size_t)kk << 15));
        uint32_t* bd = (uint32_t*)Bl;
#pragma unroll
        for (int it = 0; it < 8; ++it) {
          const int idx = it * 256 + t, row = idx >> 4, kw = idx & 15;
          bd[row * 20 + kw] = bsrc[row * 128 + ks * 16 + kw];
        }
      }
      __syncthreads();
      f16x8 af = *(const f16x8*)&SMc[(16 * w + lr) * 264 + ks * 32 + lg * 8];
#pragma unroll
      for (int nt = 0; nt < 8; ++nt) {
        f16x8 bf = *(const f16x8*)&Bl[nt * 16 + lr][lg * 8];
        acc[nt] = __builtin_amdgcn_mfma_f32_16x16x32_f16(af, bf, acc[nt], 0, 0, 0);
      }
    }
    // ---- preds epilogue: bias + row l2norm -> P ----
    {
      float v[8][4];
#pragma unroll
      for (int nt = 0; nt < 8; ++nt) {
        const float bb = wkb[kk * 128 + nt * 16 + lr];
#pragma unroll
        for (int r = 0; r < 4; ++r) v[nt][r] = acc[nt][r] + bb;
      }
#pragma unroll
      for (int r = 0; r < 4; ++r) {
        float ss = 0.f;
#pragma unroll
        for (int nt = 0; nt < 8; ++nt) ss += v[nt][r] * v[nt][r];
        ss += __shfl_xor(ss, 1); ss += __shfl_xor(ss, 2); ss += __shfl_xor(ss, 4); ss += __shfl_xor(ss, 8);
        const float scl = 1.f / fmaxf(sqrtf(ss), 1e-12f);
#pragma unroll
        for (int nt = 0; nt < 8; ++nt)
          P[16 * w + lg * 4 + r][nt * 16 + lr] = (f16)(v[nt][r] * scl);
      }
    }
    __syncthreads();
    // ---- logits + online LSE/pos/negmax over 4 s-chunks ----
    float m_run[4], s_run[4], pos_v[4], neg_m[4];
#pragma unroll
    for (int r = 0; r < 4; ++r) { m_run[r] = -1e30f; s_run[r] = 0.f; pos_v[r] = -1e30f; neg_m[r] = -1e30f; }
    for (int sc = 0; sc < 4; ++sc) {
      __syncthreads();
      {
        const uint32_t* zsrc = (const uint32_t*)(zf16 + ((size_t)b * 256 + sc * 64) * 128);
        uint32_t* zd = (uint32_t*)Zl;
#pragma unroll
        for (int it = 0; it < 16; ++it) {
          const int idx = it * 256 + t, row = idx >> 6, cw = idx & 63;
          zd[row * 68 + cw] = zsrc[row * 64 + cw];
        }
      }
      __syncthreads();
      f32x4 sa[4] = {};
#pragma unroll
      for (int ks = 0; ks < 4; ++ks) {
        f16x8 af = *(const f16x8*)&P[16 * w + lr][ks * 32 + lg * 8];
#pragma unroll
        for (int nt = 0; nt < 4; ++nt) {
          f16x8 bf = *(const f16x8*)&Zl[(nt * 16 + lr) * 136 + ks * 32 + lg * 8];
          sa[nt] = __builtin_amdgcn_mfma_f32_16x16x32_f16(af, bf, sa[nt], 0, 0, 0);
        }
      }
#pragma unroll
      for (int r = 0; r < 4; ++r) {
        const int trow = t0 + 16 * w + lg * 4 + r;
        const int pos_s = trow + kk + 1;
        float vv[4];
#pragma unroll
        for (int nt = 0; nt < 4; ++nt) vv[nt] = sa[nt][r] * 10.f;  // 1/TEMP
        float cm = fmaxf(fmaxf(vv[0], vv[1]), fmaxf(vv[2], vv[3]));
        cm = fmaxf(cm, __shfl_xor(cm, 1)); cm = fmaxf(cm, __shfl_xor(cm, 2));
        cm = fmaxf(cm, __shfl_xor(cm, 4)); cm = fmaxf(cm, __shfl_xor(cm, 8));
        const float nm = fmaxf(m_run[r], cm);
        float ps = __expf(vv[0] - nm) + __expf(vv[1] - nm) + __expf(vv[2] - nm) + __expf(vv[3] - nm);
        ps += __shfl_xor(ps, 1); ps += __shfl_xor(ps, 2); ps += __shfl_xor(ps, 4); ps += __shfl_xor(ps, 8);
        s_run[r] = s_run[r] * __expf(m_run[r] - nm) + ps;
        m_run[r] = nm;
        const int sbase = sc * 64 + lr;
#pragma unroll
        for (int nt = 0; nt < 4; ++nt) {
          const int s = sbase + nt * 16;
          if (s == pos_s) pos_v[r] = vv[nt];
          else neg_m[r] = fmaxf(neg_m[r], vv[nt]);
        }
      }
    }
    // ---- per-kk finalize into registers ----
#pragma unroll
    for (int r = 0; r < 4; ++r) {
      float pv = pos_v[r], ng = neg_m[r];
      pv = fmaxf(pv, __shfl_xor(pv, 1)); pv = fmaxf(pv, __shfl_xor(pv, 2));
      pv = fmaxf(pv, __shfl_xor(pv, 4)); pv = fmaxf(pv, __shfl_xor(pv, 8));
      ng = fmaxf(ng, __shfl_xor(ng, 1)); ng = fmaxf(ng, __shfl_xor(ng, 2));
      ng = fmaxf(ng, __shfl_xor(ng, 4)); ng = fmaxf(ng, __shfl_xor(ng, 8));
      const int trow = t0 + 16 * w + lg * 4 + r;
      if (lr == 0 && trow < 244) {
        const float lse = m_run[r] + __logf(s_run[r]);
        lsum += lse - pv;
        csum += (pv >= ng) ? 1.f : 0.f;
      }
    }
  }
  // ---- block reduce + global accumulate ----
  __syncthreads();
  if (t == 0) { red[0] = 0.f; red[1] = 0.f; }
  __syncthreads();
  if (lr == 0) { atomicAdd(&red[0], lsum); atomicAdd(&red[1], csum); }
  __syncthreads();
  if (t == 0) { atomicAdd(&accb[0], red[0]); atomicAdd(&accb[1], red[1]); }
}

__global__ void k_fin(const float* __restrict__ accb, float* __restrict__ out) {
  out[0] = accb[0] * (1.0f / NTOT_LOSS);
  out[1] = accb[1] * (100.0f / NTOT_LOSS);
}

// ---------------------------------------------------------------------------
extern "C" void kernel_launch(void* const* d_in, const int* in_sizes, int n_in,
                              void* d_out, int out_size, void* d_ws, size_t ws_size,
                              hipStream_t stream) {
  (void)in_sizes; (void)n_in; (void)out_size; (void)ws_size;
  const float* rr  = (const float*)d_in[0];
  const float* w1  = (const float*)d_in[1];
  const float* b1  = (const float*)d_in[2];
  const float* w2  = (const float*)d_in[3];
  const float* b2  = (const float*)d_in[4];
  const float* wih = (const float*)d_in[5];
  const float* whh = (const float*)d_in[6];
  const float* bih = (const float*)d_in[7];
  const float* bhh = (const float*)d_in[8];
  const float* wkw = (const float*)d_in[9];
  const float* wkb = (const float*)d_in[10];
  float* out = (float*)d_out;
  char* ws = (char*)d_ws;

  // workspace layout (R2)
  const size_t GX_B = (size_t)32768 * 768 * 2;  // 50,331,648
  f16* gx   = (f16*)ws;
  f16* h1   = (f16*)ws;  // alias: h1 dead before gx written
  f16* zf16 = (f16*)(ws + GX_B);
  f16* cf16 = (f16*)(ws + GX_B + 8388608);
  f16* w1T  = (f16*)(ws + GX_B + 8388608 + 16777216);
  f16* w2T  = w1T + 65536;
  f16* wihF = w2T + 32768;
  f16* whhF = wihF + 98304;
  f16* wkT  = whhF + 196608;
  float* accb = (float*)(wkT + 393216);

  float* zf32 = out + 2;
  float* cf32 = out + 2 + 4194304;

  k_prep<<<256, 256, 0, stream>>>(w1, w2, wih, whh, wkw, w1T, w2T, wihF, whhF, wkT, accb);
  k_gemm64<256, true, true><<<dim3(512, 4), 256, 0, stream>>>(rr, w1T, b1, h1, 256);
  k_enc2<<<dim3(512), 256, 0, stream>>>(h1, w2T, b2, zf32, zf16);
  k_gemm64<128, false, false><<<dim3(512, 12), 256, 0, stream>>>(zf16, wihF, bih, gx, 768);
  k_gru<<<128, 768, 0, stream>>>(gx, whhF, bhh, cf32, cf16);
  k_cpc<<<dim3(4, 128), 256, 0, stream>>>(cf16, zf16, wkT, wkb, accb);
  k_fin<<<1, 1, 0, stream>>>(accb, out);
}

// Round 14
// 581.390 us; speedup vs baseline: 1.7073x; 1.0744x over previous
//
#include <hip/hip_runtime.h>
#include <stdint.h>

// ============================================================================
// CPC forward on MI355X (gfx950).
// R2-R12: W_hh register residency unachievable; GRU streams W from L2.
// R13: kk-merged k_cpc regressed (block queue 24->2 deep) -> reverted to R2.
// R14 experiment: R2's W loads are 512B-strided across lanes (~4 lanes per
// 64B line -> ~4x line-traffic waste). Re-layout W chunk-major
// whhL[i 32][row 768][e 8] so each reload instr reads 1KB CONTIGUOUS per
// wave. Bit-identical math (same f16, same fdot2 order) -> absmax unchanged.
// If R2 was line-bound, W pipe drops 3072->~768 cyc/step; new bound is the
// LDS h-broadcast/VALU (~900-2300 cyc -> 100-245us k_gru).
// ============================================================================

typedef _Float16 f16;
typedef __attribute__((ext_vector_type(2))) _Float16 f16x2;
typedef __attribute__((ext_vector_type(8))) _Float16 f16x8;
typedef __attribute__((ext_vector_type(4))) float f32x4;

__device__ __forceinline__ f16x2 u2h(unsigned int x) { return __builtin_bit_cast(f16x2, x); }
__device__ __forceinline__ float sigm_(float x) { return __builtin_amdgcn_rcpf(1.f + __expf(-x)); }
__device__ __forceinline__ float tanh_(float x) { return 1.f - 2.f * __builtin_amdgcn_rcpf(__expf(2.f * x) + 1.f); }

#define NTOT_LOSS 374784.0f  // 12 * 128 * 244

// ---------------------------------------------------------------------------
// K0: convert weights to f16; W_hh goes to chunk-major whhL[i][row][e]
// (16B chunk i of row o at whhL + (i*768+o)*8 -> lane-contiguous reloads).
// ---------------------------------------------------------------------------
__global__ void k_prep(const float* __restrict__ w1, const float* __restrict__ w2,
                       const float* __restrict__ wih, const float* __restrict__ whh,
                       const float* __restrict__ wkw,
                       f16* __restrict__ w1T, f16* __restrict__ w2T, f16* __restrict__ wihF,
                       f16* __restrict__ whhL, f16* __restrict__ wkT, float* __restrict__ accb) {
  const int stride = gridDim.x * blockDim.x;
  const int tid = blockIdx.x * blockDim.x + threadIdx.x;
  if (tid == 0) { accb[0] = 0.f; accb[1] = 0.f; }
  // w1 (256k x 256n) -> w1T[n][k]
  for (int i = tid; i < 65536; i += stride) { int n = i >> 8, k = i & 255; w1T[i] = (f16)w1[k * 256 + n]; }
  // w2 (256k x 128n) -> w2T[n][k]
  for (int i = tid; i < 32768; i += stride) { int n = i >> 8, k = i & 255; w2T[i] = (f16)w2[k * 128 + n]; }
  // W_ih (768 x 128) already [N][K]
  for (int i = tid; i < 98304; i += stride) wihF[i] = (f16)wih[i];
  // W_hh (768 x 256) -> whhL[i][o][e]: chunk-major for coalesced reloads
  for (int idx = tid; idx < 196608; idx += stride) {
    const int e = idx & 7;
    const int o = (idx >> 3) % 768;
    const int i = idx / 6144;
    whhL[idx] = (f16)whh[o * 256 + i * 8 + e];
  }
  // Wk_w (12,256c,128d) -> wkT[kk][d][c]
  for (int i = tid; i < 393216; i += stride) {
    int kk = i >> 15, rem = i & 32767, d = rem >> 8, c = rem & 255;
    wkT[i] = (f16)wkw[(kk << 15) + c * 128 + d];
  }
}

// ---------------------------------------------------------------------------
// Generic 64x64-tile f16 MFMA GEMM (R2 version).
// ---------------------------------------------------------------------------
template <int KTOT, bool AF32, bool RELU>
__global__ __launch_bounds__(256) void k_gemm64(const void* __restrict__ Aptr,
                                                const f16* __restrict__ BT,
                                                const float* __restrict__ bias,
                                                f16* __restrict__ out, const int NT) {
  __shared__ __align__(16) f16 Al[64][40];
  __shared__ __align__(16) f16 Bl[64][40];
  const int m0 = blockIdx.x * 64;
  const int n0 = blockIdx.y * 64;
  const int t = threadIdx.x;
  const int w = t >> 6, l = t & 63, lr = l & 15, lg = l >> 4;
  const int arow = t >> 2, akq = (t & 3) * 8;
  f32x4 acc[4] = {};
  for (int ks = 0; ks < KTOT / 32; ++ks) {
    const int kc = ks * 32;
    __syncthreads();
    if constexpr (AF32) {
      const float* src = (const float*)Aptr + (size_t)(m0 + arow) * KTOT + kc + akq;
      float4 v0 = *(const float4*)src;
      float4 v1 = *(const float4*)(src + 4);
      f16x8 hv = {(f16)v0.x, (f16)v0.y, (f16)v0.z, (f16)v0.w,
                  (f16)v1.x, (f16)v1.y, (f16)v1.z, (f16)v1.w};
      *(f16x8*)&Al[arow][akq] = hv;
    } else {
      const f16* src = (const f16*)Aptr + (size_t)(m0 + arow) * KTOT + kc + akq;
      *(f16x8*)&Al[arow][akq] = *(const f16x8*)src;
    }
    *(f16x8*)&Bl[arow][akq] = *(const f16x8*)(BT + (size_t)(n0 + arow) * KTOT + kc + akq);
    __syncthreads();
    f16x8 af = *(const f16x8*)&Al[16 * w + lr][lg * 8];
#pragma unroll
    for (int nt = 0; nt < 4; ++nt) {
      f16x8 bf = *(const f16x8*)&Bl[nt * 16 + lr][lg * 8];
      acc[nt] = __builtin_amdgcn_mfma_f32_16x16x32_f16(af, bf, acc[nt], 0, 0, 0);
    }
  }
#pragma unroll
  for (int nt = 0; nt < 4; ++nt) {
    const int n = n0 + nt * 16 + lr;
    const float bb = bias[n];
#pragma unroll
    for (int r = 0; r < 4; ++r) {
      const int m = m0 + 16 * w + lg * 4 + r;
      float v = acc[nt][r] + bb;
      if (RELU) v = fmaxf(v, 0.f);
      out[(size_t)m * NT + n] = (f16)v;
    }
  }
}

// ---------------------------------------------------------------------------
// K2: z = l2norm(h1 @ w2T + b2). (R2 version)
// ---------------------------------------------------------------------------
__global__ __launch_bounds__(256) void k_enc2(const f16* __restrict__ A, const f16* __restrict__ BT,
                                              const float* __restrict__ bias,
                                              float* __restrict__ zf32, f16* __restrict__ zf16) {
  __shared__ __align__(16) f16 Al[64][40];
  __shared__ __align__(16) f16 Bl[128][40];
  const int m0 = blockIdx.x * 64;
  const int t = threadIdx.x;
  const int w = t >> 6, l = t & 63, lr = l & 15, lg = l >> 4;
  const int arow = t >> 2, akq = (t & 3) * 8;
  f32x4 acc[8] = {};
  for (int ks = 0; ks < 8; ++ks) {
    const int kc = ks * 32;
    __syncthreads();
    *(f16x8*)&Al[arow][akq] = *(const f16x8*)(A + (size_t)(m0 + arow) * 256 + kc + akq);
#pragma unroll
    for (int hh = 0; hh < 2; ++hh) {
      const int brow = arow + 64 * hh;
      *(f16x8*)&Bl[brow][akq] = *(const f16x8*)(BT + (size_t)brow * 256 + kc + akq);
    }
    __syncthreads();
    f16x8 af = *(const f16x8*)&Al[16 * w + lr][lg * 8];
#pragma unroll
    for (int nt = 0; nt < 8; ++nt) {
      f16x8 bf = *(const f16x8*)&Bl[nt * 16 + lr][lg * 8];
      acc[nt] = __builtin_amdgcn_mfma_f32_16x16x32_f16(af, bf, acc[nt], 0, 0, 0);
    }
  }
  float v[8][4];
#pragma unroll
  for (int nt = 0; nt < 8; ++nt) {
    const float bb = bias[nt * 16 + lr];
#pragma unroll
    for (int r = 0; r < 4; ++r) v[nt][r] = acc[nt][r] + bb;
  }
#pragma unroll
  for (int r = 0; r < 4; ++r) {
    float ss = 0.f;
#pragma unroll
    for (int nt = 0; nt < 8; ++nt) ss += v[nt][r] * v[nt][r];
    ss += __shfl_xor(ss, 1); ss += __shfl_xor(ss, 2); ss += __shfl_xor(ss, 4); ss += __shfl_xor(ss, 8);
    const float scl = 1.f / fmaxf(sqrtf(ss), 1e-12f);
    const int m = m0 + 16 * w + lg * 4 + r;
#pragma unroll
    for (int nt = 0; nt < 8; ++nt) {
      const int n = nt * 16 + lr;
      const float z = v[nt][r] * scl;
      zf32[(size_t)m * 128 + n] = z;
      zf16[(size_t)m * 128 + n] = (f16)z;
    }
  }
}

// ---------------------------------------------------------------------------
// K4: GRU scan (R2 structure; W reloads now COALESCED via whhL chunk-major).
// 128 blocks x 768 threads; thread o: gate g=o>>8, col c=o&255; W row
// streamed from L2 (compiler remat), h broadcast via wave-uniform b128.
// wv[i] address = whhL + (i*768 + o)*8 -> 64 lanes contiguous 1KB per load.
// ---------------------------------------------------------------------------
__global__ __launch_bounds__(768, 3) void k_gru(const f16* __restrict__ gx, const f16* __restrict__ whhL,
                                                const float* __restrict__ bhh,
                                                float* __restrict__ cout, f16* __restrict__ cf16) {
  __shared__ __align__(16) f16 h_lds[2][256];
  __shared__ float rz[2][256];
  const int b = blockIdx.x;
  const int o = threadIdx.x;
  const int g = o >> 8;
  const int c = o & 255;
  const f16* wbase = whhL + (size_t)o * 8;
  uint4 wv[32];
  {
#pragma unroll
    for (int i = 0; i < 32; ++i) wv[i] = *(const uint4*)(wbase + (size_t)i * 6144);
  }
  const float bh = bhh[o];
  if (o < 256) h_lds[0][o] = (f16)0.f;
  float h_own = 0.f;
  const f16* gxp = gx + (size_t)b * 256 * 768 + o;
  float* coutp = cout + (size_t)b * 256 * 256 + c;
  f16* cfp = cf16 + (size_t)b * 256 * 256 + c;
  __syncthreads();
#pragma unroll 1
  for (int tt = 0; tt < 256; ++tt) {
    const int cur = tt & 1;
    const float gxv = (float)gxp[tt * 768];
    float a0 = 0.f, a1 = 0.f, a2 = 0.f, a3 = 0.f;
    const uint4* hp = (const uint4*)(&h_lds[cur][0]);
#pragma unroll
    for (int i = 0; i < 32; ++i) {
      const uint4 hv = hp[i];  // wave-uniform address -> LDS broadcast
      a0 = __builtin_amdgcn_fdot2(u2h(wv[i].x), u2h(hv.x), a0, false);
      a1 = __builtin_amdgcn_fdot2(u2h(wv[i].y), u2h(hv.y), a1, false);
      a2 = __builtin_amdgcn_fdot2(u2h(wv[i].z), u2h(hv.z), a2, false);
      a3 = __builtin_amdgcn_fdot2(u2h(wv[i].w), u2h(hv.w), a3, false);
    }
    const float dot = (a0 + a1) + (a2 + a3) + bh;
    if (g < 2) rz[g][c] = sigm_(gxv + dot);
    __syncthreads();
    if (g == 2) {
      const float r = rz[0][c], zz = rz[1][c];
      const float n = tanh_(gxv + r * dot);
      const float hn = (1.f - zz) * n + zz * h_own;
      h_own = hn;
      h_lds[cur ^ 1][c] = (f16)hn;
      coutp[tt * 256] = hn;
      cfp[tt * 256] = (f16)hn;
    }
    __syncthreads();
  }
}

// ---------------------------------------------------------------------------
// K5: fused preds -> l2norm -> logits -> online LSE/pos/negmax -> loss&acc.
// (R2 version: grid (4,128,12), 256 threads, deep block queue.)
// ---------------------------------------------------------------------------
__global__ __launch_bounds__(256) void k_cpc(const f16* __restrict__ cf16, const f16* __restrict__ zf16,
                                             const f16* __restrict__ wkT, const float* __restrict__ wkb,
                                             float* __restrict__ accb) {
  __shared__ __align__(16) f16 SMc[64 * 264];   // c-tile [64][264], reused as z-chunk [64][136]
  __shared__ __align__(16) f16 Bl[128][40];
  __shared__ __align__(16) f16 P[64][136];
  __shared__ float red[2];
  const int tc = blockIdx.x, b = blockIdx.y, kk = blockIdx.z;
  const int t0 = tc * 64;
  const int t = threadIdx.x;
  const int w = t >> 6, l = t & 63, lr = l & 15, lg = l >> 4;
  {
    const uint32_t* src = (const uint32_t*)(cf16 + ((size_t)b * 256 + t0) * 256);
    uint32_t* dst = (uint32_t*)SMc;
#pragma unroll
    for (int it = 0; it < 32; ++it) {
      const int idx = it * 256 + t, row = idx >> 7, cw = idx & 127;
      dst[row * 132 + cw] = src[row * 128 + cw];
    }
  }
  f32x4 acc[8] = {};
  for (int ks = 0; ks < 8; ++ks) {
    __syncthreads();
    {
      const uint32_t* bsrc = (const uint32_t*)(wkT + ((size_t)kk << 15));
      uint32_t* bd = (uint32_t*)Bl;
#pragma unroll
      for (int it = 0; it < 8; ++it) {
        const int idx = it * 256 + t, row = idx >> 4, kw = idx & 15;
        bd[row * 20 + kw] = bsrc[row * 128 + ks * 16 + kw];
      }
    }
    __syncthreads();
    f16x8 af = *(const f16x8*)&SMc[(16 * w + lr) * 264 + ks * 32 + lg * 8];
#pragma unroll
    for (int nt = 0; nt < 8; ++nt) {
      f16x8 bf = *(const f16x8*)&Bl[nt * 16 + lr][lg * 8];
      acc[nt] = __builtin_amdgcn_mfma_f32_16x16x32_f16(af, bf, acc[nt], 0, 0, 0);
    }
  }
  {
    float v[8][4];
#pragma unroll
    for (int nt = 0; nt < 8; ++nt) {
      const float bb = wkb[kk * 128 + nt * 16 + lr];
#pragma unroll
      for (int r = 0; r < 4; ++r) v[nt][r] = acc[nt][r] + bb;
    }
#pragma unroll
    for (int r = 0; r < 4; ++r) {
      float ss = 0.f;
#pragma unroll
      for (int nt = 0; nt < 8; ++nt) ss += v[nt][r] * v[nt][r];
      ss += __shfl_xor(ss, 1); ss += __shfl_xor(ss, 2); ss += __shfl_xor(ss, 4); ss += __shfl_xor(ss, 8);
      const float scl = 1.f / fmaxf(sqrtf(ss), 1e-12f);
#pragma unroll
      for (int nt = 0; nt < 8; ++nt)
        P[16 * w + lg * 4 + r][nt * 16 + lr] = (f16)(v[nt][r] * scl);
    }
  }
  __syncthreads();
  float m_run[4], s_run[4], pos_v[4], neg_m[4];
#pragma unroll
  for (int r = 0; r < 4; ++r) { m_run[r] = -1e30f; s_run[r] = 0.f; pos_v[r] = -1e30f; neg_m[r] = -1e30f; }
  for (int sc = 0; sc < 4; ++sc) {
    __syncthreads();
    {
      const uint32_t* zsrc = (const uint32_t*)(zf16 + ((size_t)b * 256 + sc * 64) * 128);
      uint32_t* zd = (uint32_t*)SMc;
#pragma unroll
      for (int it = 0; it < 16; ++it) {
        const int idx = it * 256 + t, row = idx >> 6, cw = idx & 63;
        zd[row * 68 + cw] = zsrc[row * 64 + cw];
      }
    }
    __syncthreads();
    f32x4 sa[4] = {};
#pragma unroll
    for (int ks = 0; ks < 4; ++ks) {
      f16x8 af = *(const f16x8*)&P[16 * w + lr][ks * 32 + lg * 8];
#pragma unroll
      for (int nt = 0; nt < 4; ++nt) {
        f16x8 bf = *(const f16x8*)&SMc[(nt * 16 + lr) * 136 + ks * 32 + lg * 8];
        sa[nt] = __builtin_amdgcn_mfma_f32_16x16x32_f16(af, bf, sa[nt], 0, 0, 0);
      }
    }
#pragma unroll
    for (int r = 0; r < 4; ++r) {
      const int trow = t0 + 16 * w + lg * 4 + r;
      const int pos_s = trow + kk + 1;
      float vv[4];
#pragma unroll
      for (int nt = 0; nt < 4; ++nt) vv[nt] = sa[nt][r] * 10.f;  // 1/TEMP
      float cm = fmaxf(fmaxf(vv[0], vv[1]), fmaxf(vv[2], vv[3]));
      cm = fmaxf(cm, __shfl_xor(cm, 1)); cm = fmaxf(cm, __shfl_xor(cm, 2));
      cm = fmaxf(cm, __shfl_xor(cm, 4)); cm = fmaxf(cm, __shfl_xor(cm, 8));
      const float nm = fmaxf(m_run[r], cm);
      float ps = __expf(vv[0] - nm) + __expf(vv[1] - nm) + __expf(vv[2] - nm) + __expf(vv[3] - nm);
      ps += __shfl_xor(ps, 1); ps += __shfl_xor(ps, 2); ps += __shfl_xor(ps, 4); ps += __shfl_xor(ps, 8);
      s_run[r] = s_run[r] * __expf(m_run[r] - nm) + ps;
      m_run[r] = nm;
      const int sbase = sc * 64 + lr;
#pragma unroll
      for (int nt = 0; nt < 4; ++nt) {
        const int s = sbase + nt * 16;
        if (s == pos_s) pos_v[r] = vv[nt];
        else neg_m[r] = fmaxf(neg_m[r], vv[nt]);
      }
    }
  }
  __syncthreads();
  if (t == 0) { red[0] = 0.f; red[1] = 0.f; }
  __syncthreads();
  float lsum = 0.f, csum = 0.f;
#pragma unroll
  for (int r = 0; r < 4; ++r) {
    float pv = pos_v[r], ng = neg_m[r];
    pv = fmaxf(pv, __shfl_xor(pv, 1)); pv = fmaxf(pv, __shfl_xor(pv, 2));
    pv = fmaxf(pv, __shfl_xor(pv, 4)); pv = fmaxf(pv, __shfl_xor(pv, 8));
    ng = fmaxf(ng, __shfl_xor(ng, 1)); ng = fmaxf(ng, __shfl_xor(ng, 2));
    ng = fmaxf(ng, __shfl_xor(ng, 4)); ng = fmaxf(ng, __shfl_xor(ng, 8));
    const int trow = t0 + 16 * w + lg * 4 + r;
    if (lr == 0 && trow < 244) {
      const float lse = m_run[r] + __logf(s_run[r]);
      lsum += lse - pv;
      csum += (pv >= ng) ? 1.f : 0.f;
    }
  }
  if (lr == 0) { atomicAdd(&red[0], lsum); atomicAdd(&red[1], csum); }
  __syncthreads();
  if (t == 0) { atomicAdd(&accb[0], red[0]); atomicAdd(&accb[1], red[1]); }
}

__global__ void k_fin(const float* __restrict__ accb, float* __restrict__ out) {
  out[0] = accb[0] * (1.0f / NTOT_LOSS);
  out[1] = accb[1] * (100.0f / NTOT_LOSS);
}

// ---------------------------------------------------------------------------
extern "C" void kernel_launch(void* const* d_in, const int* in_sizes, int n_in,
                              void* d_out, int out_size, void* d_ws, size_t ws_size,
                              hipStream_t stream) {
  (void)in_sizes; (void)n_in; (void)out_size; (void)ws_size;
  const float* rr  = (const float*)d_in[0];
  const float* w1  = (const float*)d_in[1];
  const float* b1  = (const float*)d_in[2];
  const float* w2  = (const float*)d_in[3];
  const float* b2  = (const float*)d_in[4];
  const float* wih = (const float*)d_in[5];
  const float* whh = (const float*)d_in[6];
  const float* bih = (const float*)d_in[7];
  const float* bhh = (const float*)d_in[8];
  const float* wkw = (const float*)d_in[9];
  const float* wkb = (const float*)d_in[10];
  float* out = (float*)d_out;
  char* ws = (char*)d_ws;

  // workspace layout (R2)
  const size_t GX_B = (size_t)32768 * 768 * 2;  // 50,331,648
  f16* gx   = (f16*)ws;
  f16* h1   = (f16*)ws;  // alias: h1 dead before gx written
  f16* zf16 = (f16*)(ws + GX_B);
  f16* cf16 = (f16*)(ws + GX_B + 8388608);
  f16* w1T  = (f16*)(ws + GX_B + 8388608 + 16777216);
  f16* w2T  = w1T + 65536;
  f16* wihF = w2T + 32768;
  f16* whhL = wihF + 98304;
  f16* wkT  = whhL + 196608;
  float* accb = (float*)(wkT + 393216);

  float* zf32 = out + 2;
  float* cf32 = out + 2 + 4194304;

  k_prep<<<256, 256, 0, stream>>>(w1, w2, wih, whh, wkw, w1T, w2T, wihF, whhL, wkT, accb);
  k_gemm64<256, true, true><<<dim3(512, 4), 256, 0, stream>>>(rr, w1T, b1, h1, 256);
  k_enc2<<<dim3(512), 256, 0, stream>>>(h1, w2T, b2, zf32, zf16);
  k_gemm64<128, false, false><<<dim3(512, 12), 256, 0, stream>>>(zf16, wihF, bih, gx, 768);
  k_gru<<<128, 768, 0, stream>>>(gx, whhL, bhh, cf32, cf16);
  k_cpc<<<dim3(4, 128, 12), 256, 0, stream>>>(cf16, zf16, wkT, wkb, accb);
  k_fin<<<1, 1, 0, stream>>>(accb, out);
}